// Round 1
// baseline (17.475 us; speedup 1.0000x reference)
//
#include <hip/hip_runtime.h>

// out[b, q] = prod_{j<=q} cos(x[b, j])   (q_weights provably irrelevant:
// RZ adds diagonal phases only; CNOTs permute basis states; Z-expectations
// of the product state factorize -> Heisenberg Z_q -> Z_0..Z_q).

__global__ __launch_bounds__(256) void qlayer_kernel(
    const float* __restrict__ x, float* __restrict__ out, int batch) {
    int b = blockIdx.x * blockDim.x + threadIdx.x;
    if (b >= batch) return;
    // x row is 16 floats; we need the first 4 -> one 16B vector load.
    float4 t = *reinterpret_cast<const float4*>(x + (size_t)b * 16);
    float c0 = __cosf(t.x);
    float c1 = c0 * __cosf(t.y);
    float c2 = c1 * __cosf(t.z);
    float c3 = c2 * __cosf(t.w);
    float4 o;
    o.x = c0; o.y = c1; o.z = c2; o.w = c3;
    *reinterpret_cast<float4*>(out + (size_t)b * 4) = o;  // fully coalesced
}

extern "C" void kernel_launch(void* const* d_in, const int* in_sizes, int n_in,
                              void* d_out, int out_size, void* d_ws, size_t ws_size,
                              hipStream_t stream) {
    const float* x = (const float*)d_in[0];
    // d_in[1] (q_weights) is mathematically irrelevant to the output.
    float* out = (float*)d_out;
    int batch = in_sizes[0] / 16;  // 1048576
    int block = 256;
    int grid = (batch + block - 1) / block;  // 4096 blocks
    qlayer_kernel<<<grid, block, 0, stream>>>(x, out, batch);
}